// Round 1
// baseline (478.644 us; speedup 1.0000x reference)
//
#include <hip/hip_runtime.h>
#include <stdint.h>

#define B_ 16
#define C_ 512
#define N_ 4096
#define K_ 64
#define NUM_STAGES 3

typedef __bf16 bf16x8 __attribute__((ext_vector_type(8)));
typedef float f32x4 __attribute__((ext_vector_type(4)));

__device__ __forceinline__ uint16_t f2bf(float x) {
  union { float f; uint32_t u; } v; v.f = x;
  uint32_t r = (v.u + 0x7FFFu + ((v.u >> 16) & 1u)) >> 16;
  return (uint16_t)r;
}

__device__ __forceinline__ void async16(const uint16_t* g, uint16_t* l) {
  __builtin_amdgcn_global_load_lds(
      (const __attribute__((address_space(1))) unsigned int*)g,
      (__attribute__((address_space(3))) unsigned int*)l, 16, 0, 0);
}

// ---------------- prep: fp32 feats -> bf16 f [B][C][N] and fT [B][N][C] ----
__global__ __launch_bounds__(256) void k_prep(const float* __restrict__ feats,
                                              uint16_t* __restrict__ f16,
                                              uint16_t* __restrict__ fT16) {
  __shared__ uint16_t tile[64][65];
  int b = blockIdx.z, c0 = blockIdx.y * 64, n0 = blockIdx.x * 64;
  int t = threadIdx.x;
  const float* src = feats + ((size_t)b * C_ + c0) * N_ + n0;
  uint16_t* dst = f16 + ((size_t)b * C_ + c0) * N_ + n0;
  int cl = t >> 4;          // 0..15
  int nl = (t & 15) * 4;    // 0..60
#pragma unroll
  for (int i = 0; i < 4; ++i) {
    int c = cl + 16 * i;
    float4 v = *(const float4*)(src + (size_t)c * N_ + nl);
    ushort4 x;
    x.x = f2bf(v.x); x.y = f2bf(v.y); x.z = f2bf(v.z); x.w = f2bf(v.w);
    *(ushort4*)(dst + (size_t)c * N_ + nl) = x;
    tile[c][nl + 0] = x.x; tile[c][nl + 1] = x.y;
    tile[c][nl + 2] = x.z; tile[c][nl + 3] = x.w;
  }
  __syncthreads();
  uint16_t* dstT = fT16 + ((size_t)b * N_ + n0) * C_ + c0;
#pragma unroll
  for (int i = 0; i < 4; ++i) {
    int n = cl + 16 * i;
    int c = nl;
    ushort4 y;
    y.x = tile[c + 0][n]; y.y = tile[c + 1][n];
    y.z = tile[c + 2][n]; y.w = tile[c + 3][n];
    *(ushort4*)(dstT + (size_t)n * C_ + c) = y;
  }
}

// ---------------- init: l2norm(bases over C) -> basis [B][C][K], basisT [B][K][C]
__global__ __launch_bounds__(256) void k_init_basis(const float* __restrict__ bases,
                                                    uint16_t* __restrict__ basis,
                                                    uint16_t* __restrict__ basisT) {
  int b = blockIdx.x;
  int t = threadIdx.x;
  __shared__ float red[256];
  __shared__ float inv[64];
  int k = t & 63;
  float s = 0.f;
  for (int c = (t >> 6); c < C_; c += 4) {
    float v = bases[c * K_ + k];
    s += v * v;
  }
  red[t] = s;
  __syncthreads();
  if (t < 64) {
    float tot = red[t] + red[t + 64] + red[t + 128] + red[t + 192];
    inv[t] = 1.f / (1e-6f + sqrtf(tot));
  }
  __syncthreads();
  uint16_t* ob = basis + (size_t)b * C_ * K_;
  for (int i = 0; i < (C_ * K_) / 256; ++i) {
    int idx = t + 256 * i;
    int kk = idx & 63;
    ob[idx] = f2bf(bases[idx] * inv[kk]);
  }
  uint16_t* obT = basisT + (size_t)b * K_ * C_;
  for (int i = 0; i < (C_ * K_) / 256; ++i) {
    int idx = t + 256 * i;
    int kk = idx >> 9;
    int cc = idx & 511;
    obT[idx] = f2bf(bases[cc * K_ + kk] * inv[kk]);
  }
}

// ---------------- GEMM1 + fused softmax: attn[b,n,k] = softmax_k( sum_c fT[n,c]*basisT[k,c] )
__global__ __launch_bounds__(256) void k_gemm1(const uint16_t* __restrict__ fT,
                                               const uint16_t* __restrict__ basisT,
                                               uint16_t* __restrict__ attn,    // [B][N][K]
                                               uint16_t* __restrict__ attnT) { // [B][K][N]
  __shared__ __attribute__((aligned(16))) uint16_t ldsA[64 * 64];
  __shared__ __attribute__((aligned(16))) uint16_t ldsB[64 * 64];
  int b = blockIdx.y;
  int n0 = blockIdx.x * 64;
  int t = threadIdx.x;
  int w = t >> 6, lane = t & 63, l15 = lane & 15, quad = lane >> 4;
  const uint16_t* A = fT + ((size_t)b * N_ + n0) * C_;
  const uint16_t* Bm = basisT + (size_t)b * K_ * C_;
  f32x4 acc[4] = {};
  for (int cs = 0; cs < C_; cs += 64) {
    __syncthreads();
#pragma unroll
    for (int r = 0; r < 2; ++r) {
      int e = r * 256 + t;
      int row = e >> 3, ch = e & 7;
      int sch = (ch + row) & 7;
      async16(A + (size_t)row * C_ + cs + sch * 8, ldsA + (r * 256 + (t & 192)) * 8);
    }
#pragma unroll
    for (int r = 0; r < 2; ++r) {
      int e = r * 256 + t;
      int row = e >> 3, ch = e & 7;
      int sch = (ch + row) & 7;
      async16(Bm + (size_t)row * C_ + cs + sch * 8, ldsB + (r * 256 + (t & 192)) * 8);
    }
    __syncthreads();
#pragma unroll
    for (int s = 0; s < 2; ++s) {
      int cc = s * 4 + quad;
      int ra = 16 * w + l15;
      bf16x8 af = *(const bf16x8*)(ldsA + ra * 64 + ((cc - ra) & 7) * 8);
#pragma unroll
      for (int t4 = 0; t4 < 4; ++t4) {
        int rb = 16 * t4 + l15;
        bf16x8 bv = *(const bf16x8*)(ldsB + rb * 64 + ((cc - rb) & 7) * 8);
        acc[t4] = __builtin_amdgcn_mfma_f32_16x16x32_bf16(af, bv, acc[t4], 0, 0, 0);
      }
    }
  }
  // fused softmax over k (64 values per n-row); row n=16w+quad*4+r lives in 16 lanes (l15)
  float p[4][4];
#pragma unroll
  for (int r = 0; r < 4; ++r) {
    float m = fmaxf(fmaxf(acc[0][r], acc[1][r]), fmaxf(acc[2][r], acc[3][r]));
    m = fmaxf(m, __shfl_xor(m, 1));
    m = fmaxf(m, __shfl_xor(m, 2));
    m = fmaxf(m, __shfl_xor(m, 4));
    m = fmaxf(m, __shfl_xor(m, 8));
    float s = 0.f;
#pragma unroll
    for (int t4 = 0; t4 < 4; ++t4) { p[t4][r] = __expf(acc[t4][r] - m); s += p[t4][r]; }
    s += __shfl_xor(s, 1); s += __shfl_xor(s, 2);
    s += __shfl_xor(s, 4); s += __shfl_xor(s, 8);
    float inv = 1.f / s;
#pragma unroll
    for (int t4 = 0; t4 < 4; ++t4) p[t4][r] *= inv;
  }
  // attn [N][K]
  uint16_t* oa = attn + ((size_t)b * N_ + n0 + 16 * w + quad * 4) * K_;
#pragma unroll
  for (int r = 0; r < 4; ++r) {
#pragma unroll
    for (int t4 = 0; t4 < 4; ++t4) oa[(size_t)r * K_ + 16 * t4 + l15] = f2bf(p[t4][r]);
  }
  // attnT [K][N]: 4 consecutive n per lane -> 8B store
#pragma unroll
  for (int t4 = 0; t4 < 4; ++t4) {
    ushort4 y;
    y.x = f2bf(p[t4][0]); y.y = f2bf(p[t4][1]);
    y.z = f2bf(p[t4][2]); y.w = f2bf(p[t4][3]);
    *(ushort4*)(attnT + ((size_t)b * K_ + 16 * t4 + l15) * N_ + n0 + 16 * w + quad * 4) = y;
  }
}

// ---------------- GEMM2 (split-K=4): brawT[s][b][k][c] = sum_{n in slice} f[c,n]*attnT[k,n]
__global__ __launch_bounds__(256) void k_gemm2(const uint16_t* __restrict__ f16,
                                               const uint16_t* __restrict__ attnT,
                                               float* __restrict__ brawT) {
  __shared__ __attribute__((aligned(16))) uint16_t ldsA[32 * 64];
  __shared__ __attribute__((aligned(16))) uint16_t ldsB[64 * 64];
  int b = blockIdx.z;
  int c0 = blockIdx.x * 32;
  int slice = blockIdx.y;
  int ns0 = slice * 1024;
  int t = threadIdx.x, w = t >> 6, lane = t & 63, l15 = lane & 15, quad = lane >> 4;
  int h = w >> 1, kh = w & 1;
  const uint16_t* A = f16 + ((size_t)b * C_ + c0) * N_;
  const uint16_t* Bm = attnT + (size_t)b * K_ * N_;
  f32x4 acc[2] = {};
  for (int ns = ns0; ns < ns0 + 1024; ns += 64) {
    __syncthreads();
    {
      int row = t >> 3, ch = t & 7;
      int sch = (ch + row) & 7;
      async16(A + (size_t)row * N_ + ns + sch * 8, ldsA + (t & 192) * 8);
    }
#pragma unroll
    for (int r = 0; r < 2; ++r) {
      int e = r * 256 + t;
      int row = e >> 3, ch = e & 7;
      int sch = (ch + row) & 7;
      async16(Bm + (size_t)row * N_ + ns + sch * 8, ldsB + (r * 256 + (t & 192)) * 8);
    }
    __syncthreads();
#pragma unroll
    for (int s = 0; s < 2; ++s) {
      int cc = s * 4 + quad;
      int ra = 16 * h + l15;
      bf16x8 af = *(const bf16x8*)(ldsA + ra * 64 + ((cc - ra) & 7) * 8);
#pragma unroll
      for (int t2 = 0; t2 < 2; ++t2) {
        int rb = 32 * kh + 16 * t2 + l15;
        bf16x8 bv = *(const bf16x8*)(ldsB + rb * 64 + ((cc - rb) & 7) * 8);
        acc[t2] = __builtin_amdgcn_mfma_f32_16x16x32_bf16(af, bv, acc[t2], 0, 0, 0);
      }
    }
  }
  float* out = brawT + ((size_t)slice * B_ + b) * K_ * C_;
#pragma unroll
  for (int t2 = 0; t2 < 2; ++t2) {
    int k = 32 * kh + 16 * t2 + l15;
    float4 v = make_float4(acc[t2][0], acc[t2][1], acc[t2][2], acc[t2][3]);
    *(float4*)(out + (size_t)k * C_ + c0 + 16 * h + quad * 4) = v;
  }
}

// ---------------- l2norm of b columns (over C): basisT[b][k][c] bf16
__global__ __launch_bounds__(256) void k_l2norm(const float* __restrict__ brawT,
                                                uint16_t* __restrict__ basisT) {
  int b = blockIdx.x;
  int t = threadIdx.x, w = t >> 6, lane = t & 63;
  for (int k = w; k < K_; k += 4) {
    float v[8];
#pragma unroll
    for (int j = 0; j < 8; ++j) v[j] = 0.f;
#pragma unroll
    for (int s = 0; s < 4; ++s) {
      const float* rs = brawT + (((size_t)s * B_ + b) * K_ + k) * C_ + lane * 8;
      float4 a = *(const float4*)(rs);
      float4 c4 = *(const float4*)(rs + 4);
      v[0] += a.x; v[1] += a.y; v[2] += a.z; v[3] += a.w;
      v[4] += c4.x; v[5] += c4.y; v[6] += c4.z; v[7] += c4.w;
    }
    float ss = 0.f;
#pragma unroll
    for (int j = 0; j < 8; ++j) ss += v[j] * v[j];
    ss += __shfl_xor(ss, 1); ss += __shfl_xor(ss, 2); ss += __shfl_xor(ss, 4);
    ss += __shfl_xor(ss, 8); ss += __shfl_xor(ss, 16); ss += __shfl_xor(ss, 32);
    float inv = 1.f / (1e-6f + sqrtf(ss));
    ushort4 y0, y1;
    y0.x = f2bf(v[0] * inv); y0.y = f2bf(v[1] * inv);
    y0.z = f2bf(v[2] * inv); y0.w = f2bf(v[3] * inv);
    y1.x = f2bf(v[4] * inv); y1.y = f2bf(v[5] * inv);
    y1.z = f2bf(v[6] * inv); y1.w = f2bf(v[7] * inv);
    uint16_t* o = basisT + ((size_t)b * K_ + k) * C_ + lane * 8;
    *(ushort4*)(o) = y0;
    *(ushort4*)(o + 4) = y1;
  }
}

// ---------------- transpose basisT -> basis [B][C][K]
__global__ __launch_bounds__(256) void k_transpose_basis(const uint16_t* __restrict__ basisT,
                                                         uint16_t* __restrict__ basis) {
  __shared__ uint16_t tile[64][65];
  int b = blockIdx.y, ct = blockIdx.x;
  int t = threadIdx.x;
  const uint16_t* src = basisT + (size_t)b * K_ * C_ + ct * 64;
  for (int i = 0; i < 16; ++i) {
    int idx = t + 256 * i;
    int k = idx >> 6, c = idx & 63;
    tile[k][c] = src[(size_t)k * C_ + c];
  }
  __syncthreads();
  uint16_t* dst = basis + (size_t)b * C_ * K_ + (size_t)ct * 64 * K_;
  for (int i = 0; i < 16; ++i) {
    int idx = t + 256 * i;
    int c = idx >> 6, k = idx & 63;
    dst[(size_t)c * K_ + k] = tile[k][c];
  }
}

// ---------------- recon: out[b,c,n] = sum_k basis[c,k]*attn[n,k] (fp32 out)
__global__ __launch_bounds__(256) void k_recon(const uint16_t* __restrict__ attn,
                                               const uint16_t* __restrict__ basis,
                                               float* __restrict__ out) {
  __shared__ __attribute__((aligned(16))) uint16_t ldsA[64 * 64];
  __shared__ __attribute__((aligned(16))) uint16_t ldsB[64 * 64];
  int b = blockIdx.z, c0 = blockIdx.y * 64, n0 = blockIdx.x * 64;
  int t = threadIdx.x, w = t >> 6, lane = t & 63, l15 = lane & 15, quad = lane >> 4;
  const uint16_t* A = attn + ((size_t)b * N_ + n0) * K_;
  const uint16_t* Bm = basis + ((size_t)b * C_ + c0) * K_;
#pragma unroll
  for (int r = 0; r < 2; ++r) {
    int e = r * 256 + t;
    int row = e >> 3, ch = e & 7, sch = (ch + row) & 7;
    async16(A + (size_t)row * K_ + sch * 8, ldsA + (r * 256 + (t & 192)) * 8);
  }
#pragma unroll
  for (int r = 0; r < 2; ++r) {
    int e = r * 256 + t;
    int row = e >> 3, ch = e & 7, sch = (ch + row) & 7;
    async16(Bm + (size_t)row * K_ + sch * 8, ldsB + (r * 256 + (t & 192)) * 8);
  }
  f32x4 acc[4] = {};
  __syncthreads();
#pragma unroll
  for (int s = 0; s < 2; ++s) {
    int cc = s * 4 + quad;
    int ra = 16 * w + l15;
    bf16x8 af = *(const bf16x8*)(ldsA + ra * 64 + ((cc - ra) & 7) * 8);
#pragma unroll
    for (int t4 = 0; t4 < 4; ++t4) {
      int rb = 16 * t4 + l15;
      bf16x8 bv = *(const bf16x8*)(ldsB + rb * 64 + ((cc - rb) & 7) * 8);
      acc[t4] = __builtin_amdgcn_mfma_f32_16x16x32_bf16(af, bv, acc[t4], 0, 0, 0);
    }
  }
#pragma unroll
  for (int t4 = 0; t4 < 4; ++t4) {
    int c = c0 + 16 * t4 + l15;
    float4 v = make_float4(acc[t4][0], acc[t4][1], acc[t4][2], acc[t4][3]);
    *(float4*)(out + ((size_t)b * C_ + c) * N_ + n0 + 16 * w + quad * 4) = v;
  }
}

extern "C" void kernel_launch(void* const* d_in, const int* in_sizes, int n_in,
                              void* d_out, int out_size, void* d_ws, size_t ws_size,
                              hipStream_t stream) {
  const float* feats = (const float*)d_in[0];
  const float* bases = (const float*)d_in[1];
  float* out = (float*)d_out;
  char* ws = (char*)d_ws;
  uint16_t* f16 = (uint16_t*)(ws);                         // 64 MB
  uint16_t* fT16 = (uint16_t*)(ws + 67108864);             // 64 MB
  uint16_t* attn = (uint16_t*)(ws + 134217728);            // 8 MB
  uint16_t* attnT = (uint16_t*)(ws + 142606336);           // 8 MB
  uint16_t* basis = (uint16_t*)(ws + 150994944);           // 1 MB
  uint16_t* basisT = (uint16_t*)(ws + 152043520);          // 1 MB
  float* brawT = (float*)(ws + 153092096);                 // 8 MB (4 slices)

  k_prep<<<dim3(64, 8, 16), 256, 0, stream>>>(feats, f16, fT16);
  k_init_basis<<<16, 256, 0, stream>>>(bases, basis, basisT);
  for (int st = 0; st < NUM_STAGES; ++st) {
    k_gemm1<<<dim3(64, 16), 256, 0, stream>>>(fT16, basisT, attn, attnT);
    k_gemm2<<<dim3(16, 4, 16), 256, 0, stream>>>(f16, attnT, brawT);
    k_l2norm<<<16, 256, 0, stream>>>(brawT, basisT);
    k_transpose_basis<<<dim3(8, 16), 256, 0, stream>>>(basisT, basis);
  }
  k_recon<<<dim3(64, 8, 16), 256, 0, stream>>>(attn, basis, out);
}